// Round 1
// baseline (342.679 us; speedup 1.0000x reference)
//
#include <hip/hip_runtime.h>
#include <hip/hip_bf16.h>

typedef unsigned short u16;
typedef unsigned int u32;
typedef __attribute__((ext_vector_type(8))) short bf16x8;   // 8 bf16 = 4 VGPRs
typedef __attribute__((ext_vector_type(4))) float f32x4;
typedef __attribute__((ext_vector_type(2))) unsigned int u32x2;

#define NBATCH 4
#define DDIM   128
#define NHEAD  8
#define PTOT   12544
#define CWID   112     // patch grid width
#define NTOK   49      // tokens per 7x7 window
#define PSTR   68      // p_lds row stride (u16 elems) -> lid stride 2 banks, conflict-free
#define SCALE  0.08838834764831845f

// Single-buffered LDS layout (u16 units):
//   ts  [49][128]  @ 0       (T^T, swizzled; rows >=49 never written — reads land in us, masked)
//   us  [128][64]  @ 6272    (U, swizzled)
//   pl  [49][68]   @ 14464   (P^T, wave-private rows)
//   pcf bf16[1352] @ 17796   (pos bias, bf16 to fit 4 blocks/CU)
//   cs  f32[512]   @ 19148
// total 20172 u16 = 40344 B -> 4 blocks/CU = 16 waves/CU (vs 2 blocks / 8 waves before).
// grid 1024 == 256 CU x 4 -> whole grid co-resident, single scheduling round.
#define OFF_US  6272
#define OFF_PL  14464
#define OFF_PCF 17796
#define OFF_CS  19148
#define LDS_TOT 20172

__device__ __forceinline__ float bf2f(u16 u) {
    union { u32 i; float f; } x; x.i = ((u32)u) << 16; return x.f;
}
__device__ __forceinline__ u16 f2bf(float f) {
    union { float f; u32 u; } v; v.f = f;
    return (u16)((v.u + 0x7fffu + ((v.u >> 16) & 1u)) >> 16);
}
__device__ __forceinline__ u32 pk2(float a, float b) {
    union { __hip_bfloat162 h; u32 u; } c;
    float2 t; t.x = a; t.y = b;
    c.h = __float22bfloat162_rn(t);
    return c.u;
}
__device__ __forceinline__ int swz128(int row, int col) {
    return row * 128 + ((((col >> 3) ^ (row & 15)) & 15) << 3) + (col & 7);
}

// ws layout: u16 Gt (8 x 128x128, row-major d' rows, pre-scaled) | u16 Wc (8 x 128x128) | fp32 block
// fp32 block at u16 offset 262144: bcv[1024] | r[1024] (scaled) | M[1024] (scaled) | s[8] (scaled)
#define WS_WC   131072
#define WS_F32  262144

// ---- prepass (128 blocks = 16 outputs x 8 row-slices): 8x more parallel than before ----
// b<8 -> Wc_h = Wo_h*Wv_h + bcv; b>=8 -> Gt_h = scaled (Wk^T Wq)^T + r/M/s
__global__ void __launch_bounds__(256) prep(
    const float* __restrict__ Wq, const float* __restrict__ Wk,
    const float* __restrict__ Wv, const float* __restrict__ Wo,
    const float* __restrict__ bq, const float* __restrict__ bk,
    const float* __restrict__ bv, u16* __restrict__ ws)
{
    __shared__ u16 lm[18432];           // A-slice 16x128 @0, B 128x128 @2048
    const int tid = threadIdx.x;
    const int bb  = blockIdx.x;
    const int b   = bb >> 3;            // 0..15 (which output matrix)
    const int sub = bb & 7;             // 16-row slice of the output rows
    const bool isG = (b >= 8);
    const int h = b & 7;
    const int r0 = sub * 16;
    float* fb = (float*)(ws + WS_F32);

    if (!isG) {
        for (int idx = tid; idx < 2048; idx += 256) {
            const int lr = idx >> 7, dh = idx & 127;
            lm[swz128(lr, dh)] = f2bf(Wo[(r0 + lr) * 1024 + h * 128 + dh]);
        }
        for (int idx = tid; idx < 16384; idx += 256) {
            const int dh = idx >> 7, d = idx & 127;
            lm[2048 + swz128(d, dh)] = f2bf(Wv[(h * 128 + dh) * 128 + d]);
        }
        if (sub == 0 && tid < 128) {
            float s = 0.f;
            for (int dh = 0; dh < 128; ++dh)
                s += Wo[tid * 1024 + h * 128 + dh] * bv[h * 128 + dh];
            fb[h * 128 + tid] = s;                 // bcv (unscaled)
        }
    } else {
        for (int idx = tid; idx < 2048; idx += 256) {
            const int dh = idx >> 4, lr = idx & 15;
            lm[swz128(lr, dh)] = f2bf(Wk[(h * 128 + dh) * 128 + r0 + lr]);
        }
        for (int idx = tid; idx < 16384; idx += 256) {
            const int dh = idx >> 7, dp = idx & 127;
            lm[2048 + swz128(dp, dh)] = f2bf(Wq[(h * 128 + dh) * 128 + dp]);
        }
        if (sub == 0 && tid < 128) {
            float r = 0.f, m = 0.f;
            for (int dh = 0; dh < 128; ++dh) {
                r += bk[h * 128 + dh] * Wq[(h * 128 + dh) * 128 + tid];
                m += Wk[(h * 128 + dh) * 128 + tid] * bq[h * 128 + dh];
            }
            fb[1024 + h * 128 + tid] = r * SCALE;  // r_h scaled
            fb[2048 + h * 128 + tid] = m * SCALE;  // M_h scaled
        }
        if (sub == 0 && tid == 0) {
            float s = 0.f;
            for (int dh = 0; dh < 128; ++dh) s += bk[h * 128 + dh] * bq[h * 128 + dh];
            fb[3072 + h] = s * SCALE;              // s_h scaled
        }
    }
    __syncthreads();

    const int w = tid >> 6, lane = tid & 63, quad = lane >> 4, lid = lane & 15;
    const f32x4 z4 = {0.f, 0.f, 0.f, 0.f};
    u16* dst = ws + (isG ? 0 : WS_WC) + h * 16384;
    const float gs = isG ? SCALE : 1.0f;
    bf16x8 A[4];
    #pragma unroll
    for (int kt = 0; kt < 4; ++kt)
        A[kt] = *(const bf16x8*)(lm + swz128(lid, kt * 32 + quad * 8));
    #pragma unroll
    for (int ntl = 0; ntl < 2; ++ntl) {
        const int nt = 2 * w + ntl;
        f32x4 acc = z4;
        #pragma unroll
        for (int kt = 0; kt < 4; ++kt) {
            bf16x8 B = *(const bf16x8*)(lm + 2048 + swz128(nt * 16 + lid, kt * 32 + quad * 8));
            acc = __builtin_amdgcn_mfma_f32_16x16x32_bf16(A[kt], B, acc, 0, 0, 0);
        }
        #pragma unroll
        for (int r = 0; r < 4; ++r) {
            const int row = r0 + quad * 4 + r, col = nt * 16 + lid;
            if (isG) dst[col * 128 + row] = f2bf(acc[r] * gs);   // Gt[d'][d] row-major
            else     dst[row * 128 + col] = f2bf(acc[r]);        // Wc[dd][d] row-major
        }
    }
}

// 256 threads = 4 waves; wave w owns query group j in [16w,16w+16).
// Single-buffered ts/us (2 barriers per head) so LDS fits 4 blocks/CU:
// the whole 1024-block grid is co-resident (16 waves/CU) — cross-block TLP
// hides the per-head barrier + L2-load latency that dominated at 2 blocks/CU.
__global__ void __launch_bounds__(256, 4)
winattn(const float* __restrict__ xg, const u16* __restrict__ ws,
        const float* __restrict__ bo, const float* __restrict__ posf,
        float* __restrict__ out)
{
    __shared__ __align__(16) u16 sm[LDS_TOT];
    u16* xw    = sm;                      // staging overlay on ts (49*128 = 6272, exact fit)
    u16* pl    = sm + OFF_PL;             // P^T [j][i], wave-private rows
    u16* pcf16 = sm + OFF_PCF;            // pos bias, bf16
    float* cs  = (float*)(sm + OFF_CS);   // c_i per head

    const int tid  = threadIdx.x;
    const int w    = tid >> 6;
    const int lane = tid & 63;
    const int quad = lane >> 4;
    const int lid  = lane & 15;
    const int bx   = blockIdx.x;
    const int n    = bx >> 8;
    const int win  = bx & 255;
    const int pbase = (win >> 4) * 7 * CWID + (win & 15) * 7;

    const bf16x8 zf = {0,0,0,0,0,0,0,0};
    const f32x4  z4 = {0.f,0.f,0.f,0.f};

    const u16* Gt  = ws;
    const u16* Wcw = ws + WS_WC;
    const float* fb  = (const float*)(ws + WS_F32);
    const float* bcv = fb;
    const float* rP  = fb + 1024;
    const float* MP  = fb + 2048;
    const float* sP  = fb + 3072;

    // ---- stage pos table (bf16) + x window ----
    for (int i = tid; i < 169 * NHEAD; i += 256) pcf16[i] = f2bf(posf[i]);
    const float* xn = xg + n * DDIM * PTOT;
    for (int idx = tid; idx < DDIM * NTOK; idx += 256) {
        int d = idx / NTOK;
        int t = idx - d * NTOK;
        int a = t / 7, b = t - a * 7;
        xw[swz128(t, d)] = f2bf(xn[d * PTOT + pbase + a * CWID + b]);
    }
    __syncthreads();

    // ---- hoist x fragments (A-layout == B-layout: lane lid = token, quad*8 = d) ----
    bf16x8 xfrag[4][4];
    #pragma unroll
    for (int mt = 0; mt < 4; ++mt)
        #pragma unroll
        for (int kt = 0; kt < 4; ++kt)
            xfrag[mt][kt] = (mt * 16 + lid < NTOK)
                ? *(const bf16x8*)(xw + swz128(mt * 16 + lid, kt * 32 + quad * 8)) : zf;
    const int j = 16 * w + lid;
    bf16x8 xq[4];
    #pragma unroll
    for (int kt = 0; kt < 4; ++kt)
        xq[kt] = (j < NTOK)
            ? *(const bf16x8*)(xw + swz128(j, kt * 32 + quad * 8)) : zf;

    // ---- c_i tables (scaled): cs[h][i] = x_i . M_h + s_h  (MP from global/L2) ----
    for (int hh = w; hh < NHEAD; hh += 4) {
        const float sh = sP[hh];
        #pragma unroll
        for (int mt = 0; mt < 4; ++mt) {
            float c = 0.f;
            #pragma unroll
            for (int kt = 0; kt < 4; ++kt)
                #pragma unroll
                for (int jj = 0; jj < 8; ++jj)
                    c += bf2f((u16)xfrag[mt][kt][jj]) * MP[hh * 128 + kt * 32 + quad * 8 + jj];
            c += __shfl_xor(c, 16);
            c += __shfl_xor(c, 32);
            if (quad == 0) cs[hh * 64 + mt * 16 + lid] = c + sh;
        }
    }
    __syncthreads();   // xw dead (ts overlays it); cs visible

    f32x4 outacc[8];
    #pragma unroll
    for (int nt = 0; nt < 8; ++nt) outacc[nt] = z4;

    const int jc = j < NTOK ? j : NTOK - 1;

    u16* tsb = sm;               // T^T stored as ts[i<49][d'] swizzled
    u16* usb = sm + OFF_US;      // U stored as us[dd][i] swizzled

    for (int h = 0; h < NHEAD; ++h) {
        // ======== stage A: T^T = G_h x X^T (+r)  — packed 8B stores, rows <49 only ========
        #pragma unroll
        for (int mtl = 0; mtl < 2; ++mtl) {
            const int mt = 2 * w + mtl;             // d'-tile
            bf16x8 A[4];
            #pragma unroll
            for (int kt = 0; kt < 4; ++kt)
                A[kt] = *(const bf16x8*)(Gt + h * 16384 + (mt * 16 + lid) * 128 + kt * 32 + quad * 8);
            const f32x4 rb = *(const f32x4*)(rP + h * 128 + mt * 16 + quad * 4);
            const int dpb = mt * 16 + quad * 4;     // d' base for this lane's 4 outputs
            #pragma unroll
            for (int nt = 0; nt < 4; ++nt) {        // i-tiles
                f32x4 acc = z4;
                #pragma unroll
                for (int kt = 0; kt < 4; ++kt)
                    acc = __builtin_amdgcn_mfma_f32_16x16x32_bf16(A[kt], xfrag[nt][kt], acc, 0, 0, 0);
                const int i = nt * 16 + lid;
                if (i < NTOK) {                     // ts has only 49 rows now
                    u32x2 pkv;
                    pkv.x = pk2(acc[0] + rb[0], acc[1] + rb[1]);
                    pkv.y = pk2(acc[2] + rb[2], acc[3] + rb[3]);
                    *(u32x2*)(tsb + i * 128 + ((((dpb >> 3) ^ (i & 15)) & 15) << 3) + (dpb & 7)) = pkv;
                }
            }
        }
        // ======== stage A: U = X x Wc_h^T (+bcv) — packed 8B stores ========
        #pragma unroll
        for (int ntl = 0; ntl < 2; ++ntl) {
            const int nt = 2 * w + ntl;             // dd-tile
            bf16x8 B[4];
            #pragma unroll
            for (int kt = 0; kt < 4; ++kt)
                B[kt] = *(const bf16x8*)(Wcw + h * 16384 + (nt * 16 + lid) * 128 + kt * 32 + quad * 8);
            const int dd = nt * 16 + lid;
            const float bb = bcv[h * 128 + dd];
            #pragma unroll
            for (int mt = 0; mt < 4; ++mt) {        // i-tiles
                f32x4 acc = z4;
                #pragma unroll
                for (int kt = 0; kt < 4; ++kt)
                    acc = __builtin_amdgcn_mfma_f32_16x16x32_bf16(xfrag[mt][kt], B[kt], acc, 0, 0, 0);
                const int ib = mt * 16 + quad * 4;  // i base
                u32x2 pkv;
                pkv.x = pk2(acc[0] + bb, acc[1] + bb);
                pkv.y = pk2(acc[2] + bb, acc[3] + bb);
                *(u32x2*)(usb + dd * 64 + ((((ib >> 3) ^ (dd & 7)) & 7) << 3) + (ib & 7)) = pkv;
            }
        }
        __syncthreads();   // A done; B/C may read

        // ======== stage B: S = T x X_j^T (+cs+pos), softmax, P write ========
        // A-row reads for i in [49,64) land in the us region: finite bf16, masked below.
        f32x4 S[4];
        #pragma unroll
        for (int mt = 0; mt < 4; ++mt) {
            S[mt] = z4;
            #pragma unroll
            for (int kt = 0; kt < 4; ++kt) {
                bf16x8 A = *(const bf16x8*)(tsb + (mt * 16 + lid) * 128 + ((((kt * 4 + quad) ^ lid) & 15) << 3));
                S[mt] = __builtin_amdgcn_mfma_f32_16x16x32_bf16(A, xq[kt], S[mt], 0, 0, 0);
            }
        }
        const int aj = jc / 7, bj = jc - aj * 7;
        float sv[4][4];
        float mx = -3.0e38f;
        #pragma unroll
        for (int mt = 0; mt < 4; ++mt)
            #pragma unroll
            for (int r = 0; r < 4; ++r) {
                const int ii = mt * 16 + quad * 4 + r;
                float vvv;
                if (ii < NTOK) {
                    const int ai = ii / 7, bi = ii - ai * 7;
                    const int rel = (ai - aj + 6) + 13 * (bi - bj + 6);
                    vvv = S[mt][r] + cs[h * 64 + ii] + bf2f(pcf16[rel * NHEAD + h]);
                } else {
                    vvv = -3.0e38f;
                }
                sv[mt][r] = vvv;
                mx = fmaxf(mx, vvv);
            }
        mx = fmaxf(mx, __shfl_xor(mx, 16));
        mx = fmaxf(mx, __shfl_xor(mx, 32));
        float ssum = 0.f;
        #pragma unroll
        for (int mt = 0; mt < 4; ++mt)
            #pragma unroll
            for (int r = 0; r < 4; ++r) {
                const float e = __expf(sv[mt][r] - mx);
                sv[mt][r] = e;
                ssum += e;
            }
        ssum += __shfl_xor(ssum, 16);
        ssum += __shfl_xor(ssum, 32);
        const float inv = 1.0f / ssum;
        if (j < NTOK) {
            #pragma unroll
            for (int mt = 0; mt < 4; ++mt) {
                u32x2 pkv;
                pkv.x = pk2(sv[mt][0] * inv, sv[mt][1] * inv);
                pkv.y = pk2(sv[mt][2] * inv, sv[mt][3] * inv);
                *(u32x2*)(pl + j * PSTR + mt * 16 + quad * 4) = pkv;
            }
        }
        __threadfence_block();   // P rows wave-private: drain + no-reorder suffices

        // ======== stage C: outacc += P^T x U ========
        #pragma unroll
        for (int kt = 0; kt < 2; ++kt) {
            union { bf16x8 v; u32 u[4]; } Af;
            #pragma unroll
            for (int q2 = 0; q2 < 4; ++q2)
                Af.u[q2] = *(const u32*)(pl + jc * PSTR + kt * 32 + quad * 8 + 2 * q2);
            #pragma unroll
            for (int nt = 0; nt < 8; ++nt) {
                const int dd = nt * 16 + lid;
                bf16x8 Bu = *(const bf16x8*)(usb + dd * 64 + ((((kt * 4 + quad) ^ (dd & 7)) & 7) << 3));
                outacc[nt] = __builtin_amdgcn_mfma_f32_16x16x32_bf16(Af.v, Bu, outacc[nt], 0, 0, 0);
            }
        }
        if (h < NHEAD - 1) __syncthreads();   // single buffer: next head rewrites ts/us
    }

    // ======== epilogue: out[n][dd][p(j)] = acc + bo[dd]  (fp32 output) ========
    float* outp = out + n * DDIM * PTOT;
    #pragma unroll
    for (int nt = 0; nt < 8; ++nt) {
        const int dd = nt * 16 + lid;
        const float bov = bo[dd];
        #pragma unroll
        for (int r = 0; r < 4; ++r) {
            const int jj = 16 * w + quad * 4 + r;
            if (jj < NTOK) {
                const int a = jj / 7, b = jj - a * 7;
                outp[dd * PTOT + pbase + a * CWID + b] = outacc[nt][r] + bov;
            }
        }
    }
}

extern "C" void kernel_launch(void* const* d_in, const int* in_sizes, int n_in,
                              void* d_out, int out_size, void* d_ws, size_t ws_size,
                              hipStream_t stream) {
    (void)in_sizes; (void)n_in; (void)ws_size; (void)out_size;
    prep<<<128, 256, 0, stream>>>((const float*)d_in[1], (const float*)d_in[3],
                                  (const float*)d_in[5], (const float*)d_in[7],
                                  (const float*)d_in[2], (const float*)d_in[4],
                                  (const float*)d_in[6], (u16*)d_ws);
    winattn<<<NBATCH * 256, 256, 0, stream>>>(
        (const float*)d_in[0], (const u16*)d_ws,
        (const float*)d_in[8], (const float*)d_in[9], (float*)d_out);
}

// Round 2
// 236.407 us; speedup vs baseline: 1.4495x; 1.4495x over previous
//
#include <hip/hip_runtime.h>
#include <hip/hip_bf16.h>

typedef unsigned short u16;
typedef unsigned int u32;
typedef __attribute__((ext_vector_type(8))) short bf16x8;   // 8 bf16 = 4 VGPRs
typedef __attribute__((ext_vector_type(4))) float f32x4;
typedef __attribute__((ext_vector_type(2))) unsigned int u32x2;

#define NBATCH 4
#define DDIM   128
#define NHEAD  8
#define PTOT   12544
#define CWID   112     // patch grid width
#define NTOK   49      // tokens per 7x7 window
#define PSTR   68      // p_lds row stride (u16 elems) -> lid stride 2 banks, conflict-free
#define SCALE  0.08838834764831845f

// Single-buffered LDS layout (u16 units):
//   ts  [49][128]  @ 0       (T^T, swizzled; rows >=49 never written — reads land in us, masked)
//   us  [128][64]  @ 6272    (U, swizzled)
//   pl  [49][68]   @ 14464   (P^T, wave-private rows)
//   pcf bf16[1352] @ 17796   (pos bias, bf16 to fit 4 blocks/CU)
//   cs  f32[512]   @ 19148
// total 20172 u16 = 40344 B -> 4 blocks/CU possible from the LDS side.
// VGPR must stay <=128 for 4 waves/SIMD: bound (256,2) — (256,4) forced a
// 64-VGPR budget and spilled ~770 MB of scratch traffic (round-1 post-mortem).
#define OFF_US  6272
#define OFF_PL  14464
#define OFF_PCF 17796
#define OFF_CS  19148
#define LDS_TOT 20172

__device__ __forceinline__ float bf2f(u16 u) {
    union { u32 i; float f; } x; x.i = ((u32)u) << 16; return x.f;
}
__device__ __forceinline__ u16 f2bf(float f) {
    union { float f; u32 u; } v; v.f = f;
    return (u16)((v.u + 0x7fffu + ((v.u >> 16) & 1u)) >> 16);
}
__device__ __forceinline__ u32 pk2(float a, float b) {
    union { __hip_bfloat162 h; u32 u; } c;
    float2 t; t.x = a; t.y = b;
    c.h = __float22bfloat162_rn(t);
    return c.u;
}
__device__ __forceinline__ int swz128(int row, int col) {
    return row * 128 + ((((col >> 3) ^ (row & 15)) & 15) << 3) + (col & 7);
}

// ws layout: u16 Gt (8 x 128x128, row-major d' rows, pre-scaled) | u16 Wc (8 x 128x128) | fp32 block
// fp32 block at u16 offset 262144: bcv[1024] | r[1024] (scaled) | M[1024] (scaled) | s[8] (scaled)
#define WS_WC   131072
#define WS_F32  262144

// ---- prepass (128 blocks = 16 outputs x 8 row-slices) ----
// b<8 -> Wc_h = Wo_h*Wv_h + bcv; b>=8 -> Gt_h = scaled (Wk^T Wq)^T + r/M/s
__global__ void __launch_bounds__(256) prep(
    const float* __restrict__ Wq, const float* __restrict__ Wk,
    const float* __restrict__ Wv, const float* __restrict__ Wo,
    const float* __restrict__ bq, const float* __restrict__ bk,
    const float* __restrict__ bv, u16* __restrict__ ws)
{
    __shared__ u16 lm[18432];           // A-slice 16x128 @0, B 128x128 @2048
    const int tid = threadIdx.x;
    const int bb  = blockIdx.x;
    const int b   = bb >> 3;            // 0..15 (which output matrix)
    const int sub = bb & 7;             // 16-row slice of the output rows
    const bool isG = (b >= 8);
    const int h = b & 7;
    const int r0 = sub * 16;
    float* fb = (float*)(ws + WS_F32);

    if (!isG) {
        for (int idx = tid; idx < 2048; idx += 256) {
            const int lr = idx >> 7, dh = idx & 127;
            lm[swz128(lr, dh)] = f2bf(Wo[(r0 + lr) * 1024 + h * 128 + dh]);
        }
        for (int idx = tid; idx < 16384; idx += 256) {
            const int dh = idx >> 7, d = idx & 127;
            lm[2048 + swz128(d, dh)] = f2bf(Wv[(h * 128 + dh) * 128 + d]);
        }
        if (sub == 0 && tid < 128) {
            float s = 0.f;
            for (int dh = 0; dh < 128; ++dh)
                s += Wo[tid * 1024 + h * 128 + dh] * bv[h * 128 + dh];
            fb[h * 128 + tid] = s;                 // bcv (unscaled)
        }
    } else {
        for (int idx = tid; idx < 2048; idx += 256) {
            const int dh = idx >> 4, lr = idx & 15;
            lm[swz128(lr, dh)] = f2bf(Wk[(h * 128 + dh) * 128 + r0 + lr]);
        }
        for (int idx = tid; idx < 16384; idx += 256) {
            const int dh = idx >> 7, dp = idx & 127;
            lm[2048 + swz128(dp, dh)] = f2bf(Wq[(h * 128 + dh) * 128 + dp]);
        }
        if (sub == 0 && tid < 128) {
            float r = 0.f, m = 0.f;
            for (int dh = 0; dh < 128; ++dh) {
                r += bk[h * 128 + dh] * Wq[(h * 128 + dh) * 128 + tid];
                m += Wk[(h * 128 + dh) * 128 + tid] * bq[h * 128 + dh];
            }
            fb[1024 + h * 128 + tid] = r * SCALE;  // r_h scaled
            fb[2048 + h * 128 + tid] = m * SCALE;  // M_h scaled
        }
        if (sub == 0 && tid == 0) {
            float s = 0.f;
            for (int dh = 0; dh < 128; ++dh) s += bk[h * 128 + dh] * bq[h * 128 + dh];
            fb[3072 + h] = s * SCALE;              // s_h scaled
        }
    }
    __syncthreads();

    const int w = tid >> 6, lane = tid & 63, quad = lane >> 4, lid = lane & 15;
    const f32x4 z4 = {0.f, 0.f, 0.f, 0.f};
    u16* dst = ws + (isG ? 0 : WS_WC) + h * 16384;
    const float gs = isG ? SCALE : 1.0f;
    bf16x8 A[4];
    #pragma unroll
    for (int kt = 0; kt < 4; ++kt)
        A[kt] = *(const bf16x8*)(lm + swz128(lid, kt * 32 + quad * 8));
    #pragma unroll
    for (int ntl = 0; ntl < 2; ++ntl) {
        const int nt = 2 * w + ntl;
        f32x4 acc = z4;
        #pragma unroll
        for (int kt = 0; kt < 4; ++kt) {
            bf16x8 B = *(const bf16x8*)(lm + 2048 + swz128(nt * 16 + lid, kt * 32 + quad * 8));
            acc = __builtin_amdgcn_mfma_f32_16x16x32_bf16(A[kt], B, acc, 0, 0, 0);
        }
        #pragma unroll
        for (int r = 0; r < 4; ++r) {
            const int row = r0 + quad * 4 + r, col = nt * 16 + lid;
            if (isG) dst[col * 128 + row] = f2bf(acc[r] * gs);   // Gt[d'][d] row-major
            else     dst[row * 128 + col] = f2bf(acc[r]);        // Wc[dd][d] row-major
        }
    }
}

// 256 threads = 4 waves; wave w owns query group j in [16w,16w+16).
// Single-buffered ts/us (2 barriers per head) so LDS fits 4 blocks/CU:
// the whole 1024-block grid is co-resident (16 waves/CU) — cross-block TLP
// hides the per-head barrier + L2-load latency that dominated at 2 blocks/CU.
__global__ void __launch_bounds__(256, 2)
winattn(const float* __restrict__ xg, const u16* __restrict__ ws,
        const float* __restrict__ bo, const float* __restrict__ posf,
        float* __restrict__ out)
{
    __shared__ __align__(16) u16 sm[LDS_TOT];
    u16* xw    = sm;                      // staging overlay on ts (49*128 = 6272, exact fit)
    u16* pl    = sm + OFF_PL;             // P^T [j][i], wave-private rows
    u16* pcf16 = sm + OFF_PCF;            // pos bias, bf16
    float* cs  = (float*)(sm + OFF_CS);   // c_i per head

    const int tid  = threadIdx.x;
    const int w    = tid >> 6;
    const int lane = tid & 63;
    const int quad = lane >> 4;
    const int lid  = lane & 15;
    const int bx   = blockIdx.x;
    const int n    = bx >> 8;
    const int win  = bx & 255;
    const int pbase = (win >> 4) * 7 * CWID + (win & 15) * 7;

    const bf16x8 zf = {0,0,0,0,0,0,0,0};
    const f32x4  z4 = {0.f,0.f,0.f,0.f};

    const u16* Gt  = ws;
    const u16* Wcw = ws + WS_WC;
    const float* fb  = (const float*)(ws + WS_F32);
    const float* bcv = fb;
    const float* rP  = fb + 1024;
    const float* MP  = fb + 2048;
    const float* sP  = fb + 3072;

    // ---- stage pos table (bf16) + x window ----
    for (int i = tid; i < 169 * NHEAD; i += 256) pcf16[i] = f2bf(posf[i]);
    const float* xn = xg + n * DDIM * PTOT;
    for (int idx = tid; idx < DDIM * NTOK; idx += 256) {
        int d = idx / NTOK;
        int t = idx - d * NTOK;
        int a = t / 7, b = t - a * 7;
        xw[swz128(t, d)] = f2bf(xn[d * PTOT + pbase + a * CWID + b]);
    }
    __syncthreads();

    // ---- hoist x fragments (A-layout == B-layout: lane lid = token, quad*8 = d) ----
    bf16x8 xfrag[4][4];
    #pragma unroll
    for (int mt = 0; mt < 4; ++mt)
        #pragma unroll
        for (int kt = 0; kt < 4; ++kt)
            xfrag[mt][kt] = (mt * 16 + lid < NTOK)
                ? *(const bf16x8*)(xw + swz128(mt * 16 + lid, kt * 32 + quad * 8)) : zf;
    const int j = 16 * w + lid;
    bf16x8 xq[4];
    #pragma unroll
    for (int kt = 0; kt < 4; ++kt)
        xq[kt] = (j < NTOK)
            ? *(const bf16x8*)(xw + swz128(j, kt * 32 + quad * 8)) : zf;

    // ---- c_i tables (scaled): cs[h][i] = x_i . M_h + s_h  (MP from global/L2) ----
    for (int hh = w; hh < NHEAD; hh += 4) {
        const float sh = sP[hh];
        #pragma unroll
        for (int mt = 0; mt < 4; ++mt) {
            float c = 0.f;
            #pragma unroll
            for (int kt = 0; kt < 4; ++kt)
                #pragma unroll
                for (int jj = 0; jj < 8; ++jj)
                    c += bf2f((u16)xfrag[mt][kt][jj]) * MP[hh * 128 + kt * 32 + quad * 8 + jj];
            c += __shfl_xor(c, 16);
            c += __shfl_xor(c, 32);
            if (quad == 0) cs[hh * 64 + mt * 16 + lid] = c + sh;
        }
    }
    __syncthreads();   // xw dead (ts overlays it); cs visible

    f32x4 outacc[8];
    #pragma unroll
    for (int nt = 0; nt < 8; ++nt) outacc[nt] = z4;

    const int jc = j < NTOK ? j : NTOK - 1;

    u16* tsb = sm;               // T^T stored as ts[i<49][d'] swizzled
    u16* usb = sm + OFF_US;      // U stored as us[dd][i] swizzled

    for (int h = 0; h < NHEAD; ++h) {
        // ======== stage A: T^T = G_h x X^T (+r)  — packed 8B stores, rows <49 only ========
        #pragma unroll
        for (int mtl = 0; mtl < 2; ++mtl) {
            const int mt = 2 * w + mtl;             // d'-tile
            bf16x8 A[4];
            #pragma unroll
            for (int kt = 0; kt < 4; ++kt)
                A[kt] = *(const bf16x8*)(Gt + h * 16384 + (mt * 16 + lid) * 128 + kt * 32 + quad * 8);
            const f32x4 rb = *(const f32x4*)(rP + h * 128 + mt * 16 + quad * 4);
            const int dpb = mt * 16 + quad * 4;     // d' base for this lane's 4 outputs
            #pragma unroll
            for (int nt = 0; nt < 4; ++nt) {        // i-tiles
                f32x4 acc = z4;
                #pragma unroll
                for (int kt = 0; kt < 4; ++kt)
                    acc = __builtin_amdgcn_mfma_f32_16x16x32_bf16(A[kt], xfrag[nt][kt], acc, 0, 0, 0);
                const int i = nt * 16 + lid;
                if (i < NTOK) {                     // ts has only 49 rows now
                    u32x2 pkv;
                    pkv.x = pk2(acc[0] + rb[0], acc[1] + rb[1]);
                    pkv.y = pk2(acc[2] + rb[2], acc[3] + rb[3]);
                    *(u32x2*)(tsb + i * 128 + ((((dpb >> 3) ^ (i & 15)) & 15) << 3) + (dpb & 7)) = pkv;
                }
            }
        }
        // ======== stage A: U = X x Wc_h^T (+bcv) — packed 8B stores ========
        #pragma unroll
        for (int ntl = 0; ntl < 2; ++ntl) {
            const int nt = 2 * w + ntl;             // dd-tile
            bf16x8 B[4];
            #pragma unroll
            for (int kt = 0; kt < 4; ++kt)
                B[kt] = *(const bf16x8*)(Wcw + h * 16384 + (nt * 16 + lid) * 128 + kt * 32 + quad * 8);
            const int dd = nt * 16 + lid;
            const float bb = bcv[h * 128 + dd];
            #pragma unroll
            for (int mt = 0; mt < 4; ++mt) {        // i-tiles
                f32x4 acc = z4;
                #pragma unroll
                for (int kt = 0; kt < 4; ++kt)
                    acc = __builtin_amdgcn_mfma_f32_16x16x32_bf16(xfrag[mt][kt], B[kt], acc, 0, 0, 0);
                const int ib = mt * 16 + quad * 4;  // i base
                u32x2 pkv;
                pkv.x = pk2(acc[0] + bb, acc[1] + bb);
                pkv.y = pk2(acc[2] + bb, acc[3] + bb);
                *(u32x2*)(usb + dd * 64 + ((((ib >> 3) ^ (dd & 7)) & 7) << 3) + (ib & 7)) = pkv;
            }
        }
        __syncthreads();   // A done; B/C may read

        // ======== stage B: S = T x X_j^T (+cs+pos), softmax, P write ========
        // A-row reads for i in [49,64) land in the us region: finite bf16, masked below.
        f32x4 S[4];
        #pragma unroll
        for (int mt = 0; mt < 4; ++mt) {
            S[mt] = z4;
            #pragma unroll
            for (int kt = 0; kt < 4; ++kt) {
                bf16x8 A = *(const bf16x8*)(tsb + (mt * 16 + lid) * 128 + ((((kt * 4 + quad) ^ lid) & 15) << 3));
                S[mt] = __builtin_amdgcn_mfma_f32_16x16x32_bf16(A, xq[kt], S[mt], 0, 0, 0);
            }
        }
        const int aj = jc / 7, bj = jc - aj * 7;
        float sv[4][4];
        float mx = -3.0e38f;
        #pragma unroll
        for (int mt = 0; mt < 4; ++mt)
            #pragma unroll
            for (int r = 0; r < 4; ++r) {
                const int ii = mt * 16 + quad * 4 + r;
                float vvv;
                if (ii < NTOK) {
                    const int ai = ii / 7, bi = ii - ai * 7;
                    const int rel = (ai - aj + 6) + 13 * (bi - bj + 6);
                    vvv = S[mt][r] + cs[h * 64 + ii] + bf2f(pcf16[rel * NHEAD + h]);
                } else {
                    vvv = -3.0e38f;
                }
                sv[mt][r] = vvv;
                mx = fmaxf(mx, vvv);
            }
        mx = fmaxf(mx, __shfl_xor(mx, 16));
        mx = fmaxf(mx, __shfl_xor(mx, 32));
        float ssum = 0.f;
        #pragma unroll
        for (int mt = 0; mt < 4; ++mt)
            #pragma unroll
            for (int r = 0; r < 4; ++r) {
                const float e = __expf(sv[mt][r] - mx);
                sv[mt][r] = e;
                ssum += e;
            }
        ssum += __shfl_xor(ssum, 16);
        ssum += __shfl_xor(ssum, 32);
        const float inv = 1.0f / ssum;
        if (j < NTOK) {
            #pragma unroll
            for (int mt = 0; mt < 4; ++mt) {
                u32x2 pkv;
                pkv.x = pk2(sv[mt][0] * inv, sv[mt][1] * inv);
                pkv.y = pk2(sv[mt][2] * inv, sv[mt][3] * inv);
                *(u32x2*)(pl + j * PSTR + mt * 16 + quad * 4) = pkv;
            }
        }
        __threadfence_block();   // P rows wave-private: drain + no-reorder suffices

        // ======== stage C: outacc += P^T x U ========
        #pragma unroll
        for (int kt = 0; kt < 2; ++kt) {
            union { bf16x8 v; u32 u[4]; } Af;
            #pragma unroll
            for (int q2 = 0; q2 < 4; ++q2)
                Af.u[q2] = *(const u32*)(pl + jc * PSTR + kt * 32 + quad * 8 + 2 * q2);
            #pragma unroll
            for (int nt = 0; nt < 8; ++nt) {
                const int dd = nt * 16 + lid;
                bf16x8 Bu = *(const bf16x8*)(usb + dd * 64 + ((((kt * 4 + quad) ^ (dd & 7)) & 7) << 3));
                outacc[nt] = __builtin_amdgcn_mfma_f32_16x16x32_bf16(Af.v, Bu, outacc[nt], 0, 0, 0);
            }
        }
        if (h < NHEAD - 1) __syncthreads();   // single buffer: next head rewrites ts/us
    }

    // ======== epilogue: out[n][dd][p(j)] = acc + bo[dd]  (fp32 output) ========
    float* outp = out + n * DDIM * PTOT;
    #pragma unroll
    for (int nt = 0; nt < 8; ++nt) {
        const int dd = nt * 16 + lid;
        const float bov = bo[dd];
        #pragma unroll
        for (int r = 0; r < 4; ++r) {
            const int jj = 16 * w + quad * 4 + r;
            if (jj < NTOK) {
                const int a = jj / 7, b = jj - a * 7;
                outp[dd * PTOT + pbase + a * CWID + b] = outacc[nt][r] + bov;
            }
        }
    }
}

extern "C" void kernel_launch(void* const* d_in, const int* in_sizes, int n_in,
                              void* d_out, int out_size, void* d_ws, size_t ws_size,
                              hipStream_t stream) {
    (void)in_sizes; (void)n_in; (void)ws_size; (void)out_size;
    prep<<<128, 256, 0, stream>>>((const float*)d_in[1], (const float*)d_in[3],
                                  (const float*)d_in[5], (const float*)d_in[7],
                                  (const float*)d_in[2], (const float*)d_in[4],
                                  (const float*)d_in[6], (u16*)d_ws);
    winattn<<<NBATCH * 256, 256, 0, stream>>>(
        (const float*)d_in[0], (const u16*)d_ws,
        (const float*)d_in[8], (const float*)d_in[9], (float*)d_out);
}